// Round 9
// baseline (141.004 us; speedup 1.0000x reference)
//
#include <hip/hip_runtime.h>
#include <hip/hip_bf16.h>

typedef __attribute__((ext_vector_type(8))) short bf16x8;
typedef __attribute__((ext_vector_type(4))) float f32x4;

static __device__ __forceinline__ f32x4 mfma16(bf16x8 a, bf16x8 b, f32x4 c) {
    return __builtin_amdgcn_mfma_f32_16x16x32_bf16(a, b, c, 0, 0, 0);
}
// async global->LDS DMA, 16 B per lane; LDS dest = wave-uniform base + lane*16
static __device__ __forceinline__ void gll16(const void* g, void* l) {
    __builtin_amdgcn_global_load_lds(
        (const __attribute__((address_space(1))) unsigned int*)g,
        (__attribute__((address_space(3))) unsigned int*)l, 16, 0, 0);
}
static __device__ __forceinline__ bf16x8 pack8(float4 a, float4 b) {
    union { bf16x8 v; __hip_bfloat162 h[4]; } u;
    u.h[0] = __float22bfloat162_rn(float2{a.x, a.y});
    u.h[1] = __float22bfloat162_rn(float2{a.z, a.w});
    u.h[2] = __float22bfloat162_rn(float2{b.x, b.y});
    u.h[3] = __float22bfloat162_rn(float2{b.z, b.w});
    return u.v;
}

#define LOG2E 1.44269504f

// ---------------- Kernel 1: QKV projection (r6 version: best measured) ----------------
// x: (2, 256, 4096) f32 ; w: (768, 256) f32
// qb[bh][n][64] linear bf16
// kb[bh][key][64] bf16, SWIZZLED: elem d stored at d ^ ((key&7)<<3)
// vt[bh][64][4096] bf16, slot-PERMUTED within 32-key groups (key 16kt+4q+r -> 8q+4kt+r)
//                        then SWIZZLED: pos p stored at p ^ ((d&7)<<3)
__global__ __launch_bounds__(256, 4) void qkv_kernel(
    const float* __restrict__ x, const float* __restrict__ w,
    __hip_bfloat16* __restrict__ qb, __hip_bfloat16* __restrict__ kb,
    __hip_bfloat16* __restrict__ vt)
{
    alignas(16) __shared__ __hip_bfloat16 sA[64 * 72];   // w tile [o][c]
    alignas(16) __shared__ __hip_bfloat16 sB[64 * 72];   // x tile transposed [n][c], c XOR-swizzled
    const int nb = blockIdx.x * 64;
    const int ob = blockIdx.y * 64;
    const int b  = blockIdx.z;
    const int tid  = threadIdx.x;
    const int lane = tid & 63;
    const int wv   = tid >> 6;
    const int quad = lane >> 4;
    const int l16  = lane & 15;

    f32x4 acc[4];
    for (int i = 0; i < 4; i++) acc[i] = (f32x4)0.f;

    // staging maps (fixed across k0)
    const int oA = tid >> 2, cA = (tid & 3) << 4;
    const float* srcw = w + (ob + oA) * 256 + cA;
    const int cB = tid >> 2, nB = (tid & 3) << 4;
    const int csw = cB ^ ((tid & 3) * 16);
    const float* srcx = x + ((size_t)b * 256 + cB) * 4096 + nb + nB;

    // prefetch k0 = 0
    float4 ra[4], rb4[4];
    #pragma unroll
    for (int i = 0; i < 4; i++) ra[i]  = *(const float4*)(srcw + i * 4);
    #pragma unroll
    for (int i = 0; i < 4; i++) rb4[i] = *(const float4*)(srcx + i * 4);

    for (int t = 0; t < 4; t++) {
        __syncthreads();   // sA/sB free (previous MFMA phase done)
        {   // A: w tile, b128 LDS stores
            union { bf16x8 v; __hip_bfloat16 h[8]; } u0, u1;
            #pragma unroll
            for (int i = 0; i < 2; i++) {
                float4 f = ra[i];
                u0.h[4*i+0] = __float2bfloat16(f.x); u0.h[4*i+1] = __float2bfloat16(f.y);
                u0.h[4*i+2] = __float2bfloat16(f.z); u0.h[4*i+3] = __float2bfloat16(f.w);
            }
            #pragma unroll
            for (int i = 0; i < 2; i++) {
                float4 f = ra[2 + i];
                u1.h[4*i+0] = __float2bfloat16(f.x); u1.h[4*i+1] = __float2bfloat16(f.y);
                u1.h[4*i+2] = __float2bfloat16(f.z); u1.h[4*i+3] = __float2bfloat16(f.w);
            }
            *(bf16x8*)&sA[oA * 72 + cA]     = u0.v;
            *(bf16x8*)&sA[oA * 72 + cA + 8] = u1.v;
        }
        {   // B: x tile, transposed scalar LDS stores (XOR-swizzled: conflict-free)
            #pragma unroll
            for (int i = 0; i < 4; i++) {
                float4 f = rb4[i];
                sB[(nB + 4*i + 0) * 72 + csw] = __float2bfloat16(f.x);
                sB[(nB + 4*i + 1) * 72 + csw] = __float2bfloat16(f.y);
                sB[(nB + 4*i + 2) * 72 + csw] = __float2bfloat16(f.z);
                sB[(nB + 4*i + 3) * 72 + csw] = __float2bfloat16(f.w);
            }
        }
        __syncthreads();   // tile ready
        if (t < 3) {       // issue k0+1 loads; latency hides under MFMA + barriers
            #pragma unroll
            for (int i = 0; i < 4; i++)
                ra[i]  = *(const float4*)(srcw + (t + 1) * 64 + i * 4);
            #pragma unroll
            for (int i = 0; i < 4; i++)
                rb4[i] = *(const float4*)(srcx + (size_t)(t + 1) * 64 * 4096 + i * 4);
        }
        const __hip_bfloat16* aRow = &sA[(16 * wv + l16) * 72];
        #pragma unroll
        for (int ks = 0; ks < 2; ks++) {
            bf16x8 af = *(const bf16x8*)&aRow[ks * 32 + quad * 8];
            #pragma unroll
            for (int ct = 0; ct < 4; ct++) {
                bf16x8 bfv = *(const bf16x8*)&sB[(16 * ct + l16) * 72
                                                 + ((ks * 32 + quad * 8) ^ (ct * 16))];
                acc[ct] = mfma16(af, bfv, acc[ct]);
            }
        }
    }
    // ---- epilogue ----
    if (ob < 512) {
        // q/k: transpose to [n][o] in LDS, then 2 contiguous b128 stores per thread
        __syncthreads();   // all waves' MFMA reads of sA/sB done
        #pragma unroll
        for (int ct = 0; ct < 4; ct++) {
            union { short4 s; __hip_bfloat16 hh[4]; } u;
            #pragma unroll
            for (int r = 0; r < 4; r++) u.hh[r] = __float2bfloat16(acc[ct][r]);
            *(short4*)&sA[(16 * ct + l16) * 72 + 16 * wv + 4 * quad] = u.s;
        }
        __syncthreads();   // cross-wave: row n holds contributions from all 4 waves
        const int n_l = tid >> 2, d16 = (tid & 3) * 16;
        const int n = nb + n_l;
        const __hip_bfloat16* srcl = &sA[n_l * 72 + d16];
        bf16x8 v0 = *(const bf16x8*)srcl;
        bf16x8 v1 = *(const bf16x8*)(srcl + 8);
        const int bhh = b * 4 + ((ob & 255) >> 6);
        if (ob < 256) {
            __hip_bfloat16* dst = qb + ((size_t)bhh * 4096 + n) * 64;
            *(bf16x8*)(dst + d16)     = v0;
            *(bf16x8*)(dst + d16 + 8) = v1;
        } else {
            const int s = (n & 7) << 3;
            __hip_bfloat16* dst = kb + ((size_t)bhh * 4096 + n) * 64;
            *(bf16x8*)(dst + (d16 ^ s))       = v0;
            *(bf16x8*)(dst + ((d16 + 8) ^ s)) = v1;
        }
    } else {
        // v: transpose 16x64 per-wave tile through LDS, then slot-permuted + swizzled stores
        __syncthreads();   // all MFMA reads of sA/sB done
        #pragma unroll
        for (int ct = 0; ct < 4; ct++)
            #pragma unroll
            for (int r = 0; r < 4; r++)
                sA[(16 * wv + quad * 4 + r) * 72 + 16 * ct + l16] = __float2bfloat16(acc[ct][r]);
        // wave-private tile rows: in-wave RAW, no barrier needed
        int o2 = (ob - 512) + 16 * wv + l16;
        int bhh = b * 4 + (o2 >> 6), d = o2 & 63;
        const __hip_bfloat16* srcl = &sA[(16 * wv + l16) * 72 + 16 * quad];
        __hip_bfloat16* vrow = vt + ((size_t)bhh * 64 + d) * 4096;
        const int kt = quad & 1;
        const int gbase = nb + (quad >> 1) * 32;
        const int dsw = (d & 7) << 3;
        #pragma unroll
        for (int m = 0; m < 4; m++) {
            short4 val = *(const short4*)(srcl + 4 * m);
            int P4 = gbase + 8 * m + 4 * kt;          // slot-permuted position
            *(short4*)(vrow + (P4 ^ dsw)) = val;      // bank swizzle
        }
    }
}

// ---------------- Kernel 2: fused flash attention + rel-pos bias ----------------
// GEOMETRY v3: 1024 blocks (64 h x 8 bh x 2 qg), 4 waves/block (2 qh x 2 kg),
// 32 q-rows/block, 64-key tiles, 64 j-iters. 4 blocks/CU (32KB dyn + 4KB static
// = 36.9KB x 4 = 147KB) -> 16 waves/CU with 4-wave barriers + r8's low-conflict
// layouts. Per-wave lifetime work identical to r3 (16q x 32k x 64j).
__global__ __launch_bounds__(256, 4) void attn_kernel(
    const __hip_bfloat16* __restrict__ qb, const __hip_bfloat16* __restrict__ kb,
    const __hip_bfloat16* __restrict__ vt, const float* __restrict__ hrel,
    const float* __restrict__ wrel, float* __restrict__ out)
{
    extern __shared__ __align__(16) char smem[];        // 32768 B: 2 x (8KB K + 8KB V)
    __shared__ __hip_bfloat16 sRH[64 * 32];             // 4096 B, TRANSPOSED [h'][q(32)]

    const int h    = blockIdx.x;
    const int bh   = blockIdx.y;
    const int qg   = blockIdx.z;    // q rows qg*32 .. +31
    const int tid  = threadIdx.x;
    const int lane = tid & 63;
    const int wv   = tid >> 6;      // 0..3
    const int qh   = wv >> 1;       // 16-q half within block
    const int kg   = wv & 1;        // 32-key slice within staged 64
    const int quad = lane >> 4;
    const int l16  = lane & 15;

    // prologue overlay (32256 B peak <= 32768)
    __hip_bfloat16* sQ   = (__hip_bfloat16*)smem;             // 32x72 (4608 B)
    __hip_bfloat16* sW   = (__hip_bfloat16*)smem + 32 * 72;   // 128x72 (18432 B)
    __hip_bfloat16* sHRs = (__hip_bfloat16*)smem + 160 * 72;  // 64x72 (9216 B)
    __hip_bfloat16* sRWt = (__hip_bfloat16*)smem;             // 32x68 overlay on sQ

    // ---- prologue staging ----
    {   // Q: this block's 32 rows
        int r = tid >> 3, d8 = (tid & 7) * 8;
        *(bf16x8*)&sQ[r * 72 + d8] =
            *(const bf16x8*)&qb[((size_t)bh * 4096 + h * 64 + qg * 32 + r) * 64 + d8];
    }
    {   // wrel: 128 rows (row 127 zero), 32 elems/thread
        int r = tid >> 1, c0 = (tid & 1) * 32;
        bf16x8 w0 = (bf16x8)(short)0, w1 = w0, w2 = w0, w3 = w0;
        if (r < 127) {
            const float* s = wrel + (size_t)r * 64 + c0;
            w0 = pack8(*(const float4*)(s),      *(const float4*)(s + 4));
            w1 = pack8(*(const float4*)(s + 8),  *(const float4*)(s + 12));
            w2 = pack8(*(const float4*)(s + 16), *(const float4*)(s + 20));
            w3 = pack8(*(const float4*)(s + 24), *(const float4*)(s + 28));
        }
        *(bf16x8*)&sW[r * 72 + c0]      = w0;
        *(bf16x8*)&sW[r * 72 + c0 + 8]  = w1;
        *(bf16x8*)&sW[r * 72 + c0 + 16] = w2;
        *(bf16x8*)&sW[r * 72 + c0 + 24] = w3;
    }
    {   // hrel rows [63-h, 127-h) -> sHRs[hp][d]
        int r = tid >> 2, c0 = (tid & 3) * 16;
        const float* s = hrel + (size_t)(63 - h + r) * 64 + c0;
        *(bf16x8*)&sHRs[r * 72 + c0]     = pack8(*(const float4*)s, *(const float4*)(s + 4));
        *(bf16x8*)&sHRs[r * 72 + c0 + 8] = pack8(*(const float4*)(s + 8),
                                                 *(const float4*)(s + 12));
    }
    __syncthreads();

    // Q fragments for this wave's 16 rows
    bf16x8 qm0, qm1;
    {
        const __hip_bfloat16* qr = &sQ[(qh * 16 + l16) * 72];
        qm0 = *(const bf16x8*)&qr[quad * 8];
        qm1 = *(const bf16x8*)&qr[32 + quad * 8];
    }
    __syncthreads();   // frags read before sRWt overwrites sQ

    // rw gather: X[w][rr] = Q . wrel[rr]; wave (qh,kg) covers its 16 q x 64 rr half.
    // scatter wp = rr + (qg*32 + wwb) - 63 -> sRWt[wwb][wp]
    {
        const int rbase = kg * 64;
        #pragma unroll
        for (int ct = 0; ct < 4; ct++) {
            int rr = rbase + 16 * ct + l16;
            f32x4 a = (f32x4)0.f;
            a = mfma16(qm0, *(const bf16x8*)&sW[rr * 72 + quad * 8], a);
            a = mfma16(qm1, *(const bf16x8*)&sW[rr * 72 + 32 + quad * 8], a);
            #pragma unroll
            for (int r = 0; r < 4; r++) {
                int wwb = 16 * qh + quad * 4 + r;
                int wp = rr + qg * 32 + wwb - 63;
                if (wp >= 0 && wp < 64) sRWt[wwb * 68 + wp] = __float2bfloat16(a[r]);
            }
        }
    }
    // rh gather -> sRH transposed [h'][q32]; wave covers h' half kg*32..+32
    {
        #pragma unroll
        for (int c = 0; c < 2; c++) {
            int hp = kg * 32 + 16 * c + l16;
            f32x4 a = (f32x4)0.f;
            a = mfma16(qm0, *(const bf16x8*)&sHRs[hp * 72 + quad * 8], a);
            a = mfma16(qm1, *(const bf16x8*)&sHRs[hp * 72 + 32 + quad * 8], a);
            #pragma unroll
            for (int r = 0; r < 4; r++)
                sRH[hp * 32 + qh * 16 + quad * 4 + r] = __float2bfloat16(a[r]);
        }
    }
    __syncthreads();

    // hoist rw bias (j-invariant per wave), pre-scaled by log2(e)
    union S4 { short4 s; __hip_bfloat16 hh[4]; };
    float rwf[2][4];
    #pragma unroll
    for (int kt = 0; kt < 2; kt++) {
        S4 t;
        t.s = *(const short4*)&sRWt[(qh * 16 + l16) * 68 + kg * 32 + 16 * kt + 4 * quad];
        #pragma unroll
        for (int r = 0; r < 4; r++)
            rwf[kt][r] = LOG2E * __bfloat162float(t.hh[r]);
    }
    __syncthreads();   // prologue LDS dead; DMA may now own smem

    // per-thread DMA source addresses (swizzle baked into global layout)
    // K tile j: 64 keys x 128 B = 8 KB; wave stages bytes [wv*2048, +2048)
    // V tile j: 64 d-rows x 128 B = 8 KB; wave stages d in [16wv, +16)
    const char* kT = (const char*)kb + (size_t)bh * 524288 + wv * 2048 + lane * 16;
    const char* vT = (const char*)vt + (size_t)bh * 524288
                     + (size_t)(16 * wv + (lane >> 3)) * 8192 + (lane & 7) * 16;

    // stage tile 0 into buf0
    gll16(kT,          smem + wv * 2048);
    gll16(kT + 1024,   smem + wv * 2048 + 1024);
    gll16(vT,          smem + 8192 + wv * 2048);
    gll16(vT + 65536,  smem + 8192 + wv * 2048 + 1024);
    __syncthreads();   // drains vmcnt: tile 0 resident

    f32x4 oacc[4];
    #pragma unroll
    for (int dt = 0; dt < 4; dt++) oacc[dt] = (f32x4)0.f;
    f32x4 lacc = (f32x4)0.f;
    const bf16x8 vones = (bf16x8)(short)0x3F80;   // bf16 1.0 broadcast

    // fragment read offsets (XOR de-swizzle; conflict-free b128)
    const int krowOff = (kg * 32 + l16) * 128;
    const int sw  = (l16 & 7) << 4;
    const int kA  = (quad * 16) ^ sw;
    const int kB  = (64 + quad * 16) ^ sw;
    const int vOff = 8192 + l16 * 128 + ((kg * 64 + quad * 16) ^ sw);

    const __hip_bfloat16* rhq = sRH + qh * 16 + l16;   // +j*32 per iter
    const float SC = 0.125f * LOG2E;

    for (int j = 0; j < 64; j++) {
        const char* buf = smem + (j & 1) * 16384;
        if (j < 63) {   // issue next-tile DMA into the other buffer (freed by last barrier)
            char* nbuf = smem + ((j + 1) & 1) * 16384;
            const char* gk = kT + (size_t)(j + 1) * 8192;
            gll16(gk,         nbuf + wv * 2048);
            gll16(gk + 1024,  nbuf + wv * 2048 + 1024);
            const char* gv = vT + (size_t)(j + 1) * 128;
            gll16(gv,         nbuf + 8192 + wv * 2048);
            gll16(gv + 65536, nbuf + 8192 + wv * 2048 + 1024);
        }

        // K fragments
        const char* kr = buf + krowOff;
        bf16x8 kf00 = *(const bf16x8*)(kr + kA);
        bf16x8 kf01 = *(const bf16x8*)(kr + kB);
        bf16x8 kf10 = *(const bf16x8*)(kr + 2048 + kA);
        bf16x8 kf11 = *(const bf16x8*)(kr + 2048 + kB);

        // S^T = mfma(K, Q): lane -> S[key=j*64+kg*32+16kt+4quad+r][q=qg*32+qh*16+l16]
        f32x4 s0 = (f32x4)0.f, s1 = (f32x4)0.f;
        __builtin_amdgcn_s_setprio(1);
        s0 = mfma16(kf00, qm0, s0);
        s0 = mfma16(kf01, qm1, s0);
        s1 = mfma16(kf10, qm0, s1);
        s1 = mfma16(kf11, qm1, s1);
        __builtin_amdgcn_s_setprio(0);

        // all keys in this tile share h' = j
        float rhb = LOG2E * __bfloat162float(rhq[j * 32]);
        float pv[8];
        #pragma unroll
        for (int r = 0; r < 4; r++)
            pv[r] = __builtin_amdgcn_exp2f(fmaf(s0[r], SC, rwf[0][r] + rhb));
        #pragma unroll
        for (int r = 0; r < 4; r++)
            pv[4 + r] = __builtin_amdgcn_exp2f(fmaf(s1[r], SC, rwf[1][r] + rhb));
        bf16x8 pa;
        {
            union { bf16x8 v; __hip_bfloat162 b2[4]; } pu;
            #pragma unroll
            for (int pi = 0; pi < 4; pi++)
                pu.b2[pi] = __float22bfloat162_rn(float2{pv[2 * pi], pv[2 * pi + 1]});
            pa = pu.v;   // slot e=4*kt+r matches vt slot layout
        }

        // O += P V ; l += P . ones  (contracts the wave's 32 keys)
        __builtin_amdgcn_s_setprio(1);
        #pragma unroll
        for (int dt = 0; dt < 4; dt++) {
            bf16x8 vf = *(const bf16x8*)(buf + vOff + dt * 2048);
            oacc[dt] = mfma16(pa, vf, oacc[dt]);
        }
        lacc = mfma16(pa, vones, lacc);
        __builtin_amdgcn_s_setprio(0);
        __syncthreads();   // drains this wave's DMA (next tile) + releases buffers
    }

    // ---- epilogue: combine the 2 key-slices (single barrier) ----
    float* obuf = (float*)smem;          // per qh: [64 d][20 q-pad] = 1280 f
    float* lbuf = obuf + 2560;           // 32 f
    if (kg == 1) {
        #pragma unroll
        for (int dt = 0; dt < 4; dt++)
            *(f32x4*)&obuf[qh * 1280 + (16 * dt + l16) * 20 + 4 * quad] = oacc[dt];
        if (l16 == 0)
            #pragma unroll
            for (int r = 0; r < 4; r++)
                lbuf[qh * 16 + 4 * quad + r] = lacc[r];
    }
    __syncthreads();
    if (kg == 0) {
        #pragma unroll
        for (int dt = 0; dt < 4; dt++)
            oacc[dt] += *(const f32x4*)&obuf[qh * 1280 + (16 * dt + l16) * 20 + 4 * quad];
        f32x4 lv;
        #pragma unroll
        for (int r = 0; r < 4; r++)
            lv[r] = 1.f / (lacc[r] + lbuf[qh * 16 + 4 * quad + r]);
        const int b = bh >> 2, head = bh & 3;
        #pragma unroll
        for (int dt = 0; dt < 4; dt++) {
            f32x4 o = oacc[dt] * lv;
            int dv = 16 * dt + l16;
            int q0 = qg * 32 + qh * 16 + 4 * quad;
            *(f32x4*)&out[((size_t)(b * 256 + head * 64 + dv)) * 4096 + h * 64 + q0] = o;
        }
    }
}

extern "C" void kernel_launch(void* const* d_in, const int* in_sizes, int n_in,
                              void* d_out, int out_size, void* d_ws, size_t ws_size,
                              hipStream_t stream) {
    const float* x     = (const float*)d_in[0];
    const float* qkv_w = (const float*)d_in[1];
    const float* hrel  = (const float*)d_in[2];
    const float* wrel  = (const float*)d_in[3];
    float* out = (float*)d_out;

    __hip_bfloat16* qb = (__hip_bfloat16*)d_ws;
    __hip_bfloat16* kb = qb + (size_t)8 * 4096 * 64;
    __hip_bfloat16* vt = kb + (size_t)8 * 4096 * 64;

    qkv_kernel<<<dim3(64, 12, 2), 256, 0, stream>>>(x, qkv_w, qb, kb, vt);
    attn_kernel<<<dim3(64, 8, 2), 256, 32768, stream>>>(qb, kb, vt, hrel, wrel, out);
}

// Round 10
// 125.476 us; speedup vs baseline: 1.1238x; 1.1238x over previous
//
#include <hip/hip_runtime.h>
#include <hip/hip_bf16.h>

typedef __attribute__((ext_vector_type(8))) short bf16x8;
typedef __attribute__((ext_vector_type(4))) float f32x4;

static __device__ __forceinline__ f32x4 mfma16(bf16x8 a, bf16x8 b, f32x4 c) {
    return __builtin_amdgcn_mfma_f32_16x16x32_bf16(a, b, c, 0, 0, 0);
}
// async global->LDS DMA, 16 B per lane; LDS dest = wave-uniform base + lane*16
static __device__ __forceinline__ void gll16(const void* g, void* l) {
    __builtin_amdgcn_global_load_lds(
        (const __attribute__((address_space(1))) unsigned int*)g,
        (__attribute__((address_space(3))) unsigned int*)l, 16, 0, 0);
}

#define LOG2E 1.44269504f

// ---------------- Kernel 1: QKV projection (paired-ob blocks) ----------------
// x: (2, 256, 4096) f32 ; w: (768, 256) f32
// Each block computes TWO output tiles (ob, ob+384) sharing one x-tile staging:
// grid 768 blocks = 3/CU (single dispatch round, no tail), B staged once per 2
// A-tiles, B-fragment reads amortized over 16 MFMA. Output layouts unchanged:
// qb[bh][n][64] linear bf16
// kb[bh][key][64] bf16, SWIZZLED: elem d stored at d ^ ((key&7)<<3)
// vt[bh][64][4096] bf16, slot-PERMUTED within 32-key groups (key 16kt+4q+r -> 8q+4kt+r)
//                        then SWIZZLED: pos p stored at p ^ ((d&7)<<3)
__global__ __launch_bounds__(256, 3) void qkv_kernel(
    const float* __restrict__ x, const float* __restrict__ w,
    __hip_bfloat16* __restrict__ qb, __hip_bfloat16* __restrict__ kb,
    __hip_bfloat16* __restrict__ vt)
{
    alignas(16) __shared__ __hip_bfloat16 sA0[64 * 72];  // w tile for ob0
    alignas(16) __shared__ __hip_bfloat16 sA1[64 * 72];  // w tile for ob1
    alignas(16) __shared__ __hip_bfloat16 sB[64 * 72];   // x tile transposed, c XOR-swizzled
    const int nb  = blockIdx.x * 64;
    const int obp = blockIdx.y;          // 0..5
    const int ob0 = obp * 64;            // always q/k (0..320)
    const int ob1 = ob0 + 384;           // k (384,448) or v (512..704)
    const int b   = blockIdx.z;
    const int tid  = threadIdx.x;
    const int lane = tid & 63;
    const int wv   = tid >> 6;
    const int quad = lane >> 4;
    const int l16  = lane & 15;

    f32x4 acc0[4], acc1[4];
    #pragma unroll
    for (int i = 0; i < 4; i++) { acc0[i] = (f32x4)0.f; acc1[i] = (f32x4)0.f; }

    // staging maps (fixed across k0)
    const int oA = tid >> 2, cA = (tid & 3) << 4;
    const float* srcw0 = w + (ob0 + oA) * 256 + cA;
    const float* srcw1 = w + (ob1 + oA) * 256 + cA;
    const int cB = tid >> 2, nB = (tid & 3) << 4;
    const int csw = cB ^ ((tid & 3) * 16);
    const float* srcx = x + ((size_t)b * 256 + cB) * 4096 + nb + nB;

    // prefetch k0 = 0
    float4 ra0[4], ra1[4], rb4[4];
    #pragma unroll
    for (int i = 0; i < 4; i++) ra0[i] = *(const float4*)(srcw0 + i * 4);
    #pragma unroll
    for (int i = 0; i < 4; i++) ra1[i] = *(const float4*)(srcw1 + i * 4);
    #pragma unroll
    for (int i = 0; i < 4; i++) rb4[i] = *(const float4*)(srcx + i * 4);

    for (int t = 0; t < 4; t++) {
        __syncthreads();   // sA/sB free (previous MFMA phase done)
        {   // A0/A1: w tiles, b128 LDS stores
            union { bf16x8 v; __hip_bfloat16 h[8]; } u;
            #pragma unroll
            for (int half = 0; half < 2; half++) {
                float4* ra = half ? ra1 : ra0;
                __hip_bfloat16* sA = half ? sA1 : sA0;
                #pragma unroll
                for (int g2 = 0; g2 < 2; g2++) {
                    #pragma unroll
                    for (int i = 0; i < 2; i++) {
                        float4 f = ra[2 * g2 + i];
                        u.h[4*i+0] = __float2bfloat16(f.x); u.h[4*i+1] = __float2bfloat16(f.y);
                        u.h[4*i+2] = __float2bfloat16(f.z); u.h[4*i+3] = __float2bfloat16(f.w);
                    }
                    *(bf16x8*)&sA[oA * 72 + cA + 8 * g2] = u.v;
                }
            }
        }
        {   // B: x tile, transposed scalar LDS stores (XOR-swizzled: conflict-free)
            #pragma unroll
            for (int i = 0; i < 4; i++) {
                float4 f = rb4[i];
                sB[(nB + 4*i + 0) * 72 + csw] = __float2bfloat16(f.x);
                sB[(nB + 4*i + 1) * 72 + csw] = __float2bfloat16(f.y);
                sB[(nB + 4*i + 2) * 72 + csw] = __float2bfloat16(f.z);
                sB[(nB + 4*i + 3) * 72 + csw] = __float2bfloat16(f.w);
            }
        }
        __syncthreads();   // tile ready
        if (t < 3) {       // issue k0+1 loads; latency hides under MFMA + barriers
            #pragma unroll
            for (int i = 0; i < 4; i++)
                ra0[i] = *(const float4*)(srcw0 + (t + 1) * 64 + i * 4);
            #pragma unroll
            for (int i = 0; i < 4; i++)
                ra1[i] = *(const float4*)(srcw1 + (t + 1) * 64 + i * 4);
            #pragma unroll
            for (int i = 0; i < 4; i++)
                rb4[i] = *(const float4*)(srcx + (size_t)(t + 1) * 64 * 4096 + i * 4);
        }
        const __hip_bfloat16* aRow0 = &sA0[(16 * wv + l16) * 72];
        const __hip_bfloat16* aRow1 = &sA1[(16 * wv + l16) * 72];
        #pragma unroll
        for (int ks = 0; ks < 2; ks++) {
            bf16x8 af0 = *(const bf16x8*)&aRow0[ks * 32 + quad * 8];
            bf16x8 af1 = *(const bf16x8*)&aRow1[ks * 32 + quad * 8];
            #pragma unroll
            for (int ct = 0; ct < 4; ct++) {
                bf16x8 bfv = *(const bf16x8*)&sB[(16 * ct + l16) * 72
                                                 + ((ks * 32 + quad * 8) ^ (ct * 16))];
                acc0[ct] = mfma16(af0, bfv, acc0[ct]);
                acc1[ct] = mfma16(af1, bfv, acc1[ct]);
            }
        }
    }
    // ---- epilogue: both halves through their own LDS scratch ----
    __syncthreads();   // all waves' MFMA reads of sA/sB done
    // writes
    #pragma unroll
    for (int ct = 0; ct < 4; ct++) {
        union { short4 s; __hip_bfloat16 hh[4]; } u;
        #pragma unroll
        for (int r = 0; r < 4; r++) u.hh[r] = __float2bfloat16(acc0[ct][r]);
        *(short4*)&sA0[(16 * ct + l16) * 72 + 16 * wv + 4 * quad] = u.s;
    }
    if (ob1 < 512) {   // half1 is k: same transpose layout
        #pragma unroll
        for (int ct = 0; ct < 4; ct++) {
            union { short4 s; __hip_bfloat16 hh[4]; } u;
            #pragma unroll
            for (int r = 0; r < 4; r++) u.hh[r] = __float2bfloat16(acc1[ct][r]);
            *(short4*)&sA1[(16 * ct + l16) * 72 + 16 * wv + 4 * quad] = u.s;
        }
    } else {           // half1 is v: row-major per-wave tile
        #pragma unroll
        for (int ct = 0; ct < 4; ct++)
            #pragma unroll
            for (int r = 0; r < 4; r++)
                sA1[(16 * wv + quad * 4 + r) * 72 + 16 * ct + l16] =
                    __float2bfloat16(acc1[ct][r]);
    }
    __syncthreads();
    // reads/stores
    {
        const int n_l = tid >> 2, d16 = (tid & 3) * 16;
        const int n = nb + n_l;
        {   // half0: q (ob0<256) or k
            const __hip_bfloat16* srcl = &sA0[n_l * 72 + d16];
            bf16x8 v0 = *(const bf16x8*)srcl;
            bf16x8 v1 = *(const bf16x8*)(srcl + 8);
            const int bhh = b * 4 + ((ob0 & 255) >> 6);
            if (ob0 < 256) {
                __hip_bfloat16* dst = qb + ((size_t)bhh * 4096 + n) * 64;
                *(bf16x8*)(dst + d16)     = v0;
                *(bf16x8*)(dst + d16 + 8) = v1;
            } else {
                const int s = (n & 7) << 3;
                __hip_bfloat16* dst = kb + ((size_t)bhh * 4096 + n) * 64;
                *(bf16x8*)(dst + (d16 ^ s))       = v0;
                *(bf16x8*)(dst + ((d16 + 8) ^ s)) = v1;
            }
        }
        if (ob1 < 512) {   // half1 k
            const __hip_bfloat16* srcl = &sA1[n_l * 72 + d16];
            bf16x8 v0 = *(const bf16x8*)srcl;
            bf16x8 v1 = *(const bf16x8*)(srcl + 8);
            const int bhh = b * 4 + ((ob1 & 255) >> 6);
            const int s = (n & 7) << 3;
            __hip_bfloat16* dst = kb + ((size_t)bhh * 4096 + n) * 64;
            *(bf16x8*)(dst + (d16 ^ s))       = v0;
            *(bf16x8*)(dst + ((d16 + 8) ^ s)) = v1;
        } else {           // half1 v: slot-permuted + swizzled stores
            int o2 = (ob1 - 512) + 16 * wv + l16;
            int bhh = b * 4 + (o2 >> 6), d = o2 & 63;
            const __hip_bfloat16* srcl = &sA1[(16 * wv + l16) * 72 + 16 * quad];
            __hip_bfloat16* vrow = vt + ((size_t)bhh * 64 + d) * 4096;
            const int kt = quad & 1;
            const int gbase = nb + (quad >> 1) * 32;
            const int dsw = (d & 7) << 3;
            #pragma unroll
            for (int m = 0; m < 4; m++) {
                short4 val = *(const short4*)(srcl + 4 * m);
                int P4 = gbase + 8 * m + 4 * kt;          // slot-permuted position
                *(short4*)(vrow + (P4 ^ dsw)) = val;      // bank swizzle
            }
        }
    }
}

// ---------------- Kernel 2: fused flash attention + rel-pos bias (r3/r6 version, UNCHANGED) ----------------
// 8 waves = 2 q-groups x 4 key-slices. Swapped QK^T keeps P in registers.
// K/V staged by global_load_lds DMA into double-buffered linear LDS (swizzle baked
// into the global layouts). Softmax denominator computed by a ones-column MFMA.
// One __syncthreads per j. NOTE: counted-vmcnt (r4), barrier-free (r5), 4-wave
// 64-key (r8), and q-split (r9) variants ALL measured worse (60.6/311/59.5/68.5
// vs ~55 us) -- this structure is the measured local optimum.
__global__ __launch_bounds__(512, 4) void attn_kernel(
    const __hip_bfloat16* __restrict__ qb, const __hip_bfloat16* __restrict__ kb,
    const __hip_bfloat16* __restrict__ vt, const float* __restrict__ hrel,
    const float* __restrict__ wrel, float* __restrict__ out)
{
    extern __shared__ __align__(16) char smem[];         // 65536 B: 2 x (16KB K + 16KB V)
    alignas(16) __shared__ __hip_bfloat16 sRH[64 * 66];  // persistent rh bias [q][h']

    const int h    = blockIdx.x;
    const int bh   = blockIdx.y;
    const int tid  = threadIdx.x;
    const int lane = tid & 63;
    const int wv   = tid >> 6;      // 0..7
    const int qg   = wv >> 2;       // q rows qg*32..+31
    const int kg   = wv & 3;        // key slice kg*32..+31 within staged 128
    const int quad = lane >> 4;
    const int l16  = lane & 15;

    // prologue overlay
    __hip_bfloat16* sQ   = (__hip_bfloat16*)smem;            // 64x72
    __hip_bfloat16* sW   = (__hip_bfloat16*)smem + 64 * 72;  // 128x72 (wrel, row 127 zero)
    __hip_bfloat16* sHRs = (__hip_bfloat16*)smem + 192 * 72; // 64x72 (shifted hrel)
    __hip_bfloat16* sRWt = (__hip_bfloat16*)smem;            // 64x68 gather scratch

    // ---- prologue staging ----
    {   // Q: 64x64 bf16 contiguous
        int r = tid >> 3, d8 = (tid & 7) * 8;
        *(bf16x8*)&sQ[r * 72 + d8] =
            *(const bf16x8*)&qb[(((size_t)bh * 4096 + h * 64 + r)) * 64 + d8];
    }
    {   // wrel: 127x64 f32 -> bf16 (row 127 zero)
        int r = tid >> 2, c0 = (tid & 3) << 4;
        union { bf16x8 v; __hip_bfloat16 h8[8]; } u0, u1;
        #pragma unroll
        for (int i = 0; i < 2; i++) {
            float4 f = (r < 127) ? *(const float4*)&wrel[r * 64 + c0 + 4*i] : float4{0,0,0,0};
            u0.h8[4*i+0] = __float2bfloat16(f.x); u0.h8[4*i+1] = __float2bfloat16(f.y);
            u0.h8[4*i+2] = __float2bfloat16(f.z); u0.h8[4*i+3] = __float2bfloat16(f.w);
        }
        #pragma unroll
        for (int i = 0; i < 2; i++) {
            float4 f = (r < 127) ? *(const float4*)&wrel[r * 64 + c0 + 8 + 4*i] : float4{0,0,0,0};
            u1.h8[4*i+0] = __float2bfloat16(f.x); u1.h8[4*i+1] = __float2bfloat16(f.y);
            u1.h8[4*i+2] = __float2bfloat16(f.z); u1.h8[4*i+3] = __float2bfloat16(f.w);
        }
        *(bf16x8*)&sW[r * 72 + c0]     = u0.v;
        *(bf16x8*)&sW[r * 72 + c0 + 8] = u1.v;
    }
    {   // hrel rows [63-h, 127-h) -> sHRs[hp][d]
        int r = tid >> 3, c0 = (tid & 7) * 8;
        union { bf16x8 v; __hip_bfloat16 h8[8]; } u0;
        #pragma unroll
        for (int i = 0; i < 2; i++) {
            float4 f = *(const float4*)&hrel[(63 - h + r) * 64 + c0 + 4*i];
            u0.h8[4*i+0] = __float2bfloat16(f.x); u0.h8[4*i+1] = __float2bfloat16(f.y);
            u0.h8[4*i+2] = __float2bfloat16(f.z); u0.h8[4*i+3] = __float2bfloat16(f.w);
        }
        *(bf16x8*)&sHRs[r * 72 + c0] = u0.v;
    }
    __syncthreads();

    // fragments: gather frags (g-mapped) + main Q frags (qg-mapped)
    const int g    = wv & 3;
    const int half = wv >> 2;
    const __hip_bfloat16* aRow = &sQ[(16 * g + l16) * 72];
    bf16x8 qf0 = *(const bf16x8*)&aRow[quad * 8];
    bf16x8 qf1 = *(const bf16x8*)&aRow[32 + quad * 8];
    bf16x8 qm[2][2];
    #pragma unroll
    for (int qt = 0; qt < 2; qt++) {
        const __hip_bfloat16* qr = &sQ[(qg * 32 + 16 * qt + l16) * 72];
        qm[qt][0] = *(const bf16x8*)&qr[quad * 8];
        qm[qt][1] = *(const bf16x8*)&qr[32 + quad * 8];
    }
    __syncthreads();   // all frags read before sRWt overwrites sQ

    // rw gather: X[w][rr] = Q . wrel[rr]; scatter wp = rr + w - 63 -> sRWt[w][wp]
    {
        const int rbase = half * 64;
        #pragma unroll
        for (int ct = 0; ct < 4; ct++) {
            int rr = rbase + 16 * ct + l16;
            f32x4 a = (f32x4)0.f;
            a = mfma16(qf0, *(const bf16x8*)&sW[rr * 72 + quad * 8], a);
            a = mfma16(qf1, *(const bf16x8*)&sW[rr * 72 + 32 + quad * 8], a);
            #pragma unroll
            for (int r = 0; r < 4; r++) {
                int ww = 16 * g + quad * 4 + r;
                int wp = rr + ww - 63;
                if (wp >= 0 && wp < 64) sRWt[ww * 68 + wp] = __float2bfloat16(a[r]);
            }
        }
    }
    // rh bias (waves 0-3): sRH[w][h'] = Q . sHRs[h']
    if (half == 0) {
        #pragma unroll
        for (int ct = 0; ct < 4; ct++) {
            f32x4 a = (f32x4)0.f;
            a = mfma16(qf0, *(const bf16x8*)&sHRs[(16 * ct + l16) * 72 + quad * 8], a);
            a = mfma16(qf1, *(const bf16x8*)&sHRs[(16 * ct + l16) * 72 + 32 + quad * 8], a);
            #pragma unroll
            for (int r = 0; r < 4; r++)
                sRH[(16 * g + quad * 4 + r) * 66 + 16 * ct + l16] = __float2bfloat16(a[r]);
        }
    }
    __syncthreads();

    // hoist rw bias (j-invariant per wave), pre-scaled by log2(e), in f32
    union S4 { short4 s; __hip_bfloat16 h[4]; };
    float rwf[2][2][4];
    #pragma unroll
    for (int qt = 0; qt < 2; qt++)
        #pragma unroll
        for (int kt = 0; kt < 2; kt++) {
            S4 t;
            t.s = *(const short4*)&sRWt[(qg * 32 + 16 * qt + l16) * 68
                                        + 32 * (kg & 1) + 16 * kt + 4 * quad];
            #pragma unroll
            for (int r = 0; r < 4; r++)
                rwf[qt][kt][r] = LOG2E * __bfloat162float(t.h[r]);
        }
    __syncthreads();   // prologue LDS dead; DMA may now own smem

    // per-thread DMA source addresses (swizzle baked into global layout)
    const char* kT = (const char*)kb + (size_t)bh * 524288 + wv * 1024 + lane * 16;
    const char* vT = (const char*)vt + (size_t)bh * 524288
                     + (size_t)(wv * 4 + quad) * 8192 + l16 * 16;

    // stage tile 0 into buf0
    gll16(kT,           smem + wv * 1024);
    gll16(kT + 8192,    smem + 8192 + wv * 1024);
    gll16(vT,           smem + 16384 + wv * 1024);
    gll16(vT + 262144,  smem + 24576 + wv * 1024);
    __syncthreads();   // drains vmcnt: tile 0 resident

    f32x4 oacc[2][4];
    #pragma unroll
    for (int qt = 0; qt < 2; qt++)
        #pragma unroll
        for (int dt = 0; dt < 4; dt++) oacc[qt][dt] = (f32x4)0.f;
    f32x4 lacc[2] = {(f32x4)0.f, (f32x4)0.f};
    const bf16x8 vones = (bf16x8)(short)0x3F80;   // bf16 1.0 broadcast

    // fragment read offsets (XOR de-swizzle; conflict-free b128)
    const int krowOff = (kg * 32 + l16) * 128;
    const int sw  = (l16 & 7) << 4;
    const int kA  = (quad * 16) ^ sw;
    const int kB  = (64 + quad * 16) ^ sw;
    const int vOff = 16384 + l16 * 256 + ((kg * 64 + quad * 16) ^ sw);

    const __hip_bfloat16* rh0 = &sRH[(qg * 32 + l16) * 66];
    const __hip_bfloat16* rh1 = &sRH[(qg * 32 + 16 + l16) * 66];
    const float SC = 0.125f * LOG2E;

    for (int j = 0; j < 32; j++) {
        const char* buf = smem + (j & 1) * 32768;
        if (j < 31) {   // issue next-tile DMA into the other buffer (freed by last barrier)
            char* nbuf = smem + ((j + 1) & 1) * 32768;
            const char* gk = kT + (size_t)(j + 1) * 16384;
            gll16(gk,          nbuf + wv * 1024);
            gll16(gk + 8192,   nbuf + 8192 + wv * 1024);
            const char* gv = vT + (size_t)(j + 1) * 256;
            gll16(gv,          nbuf + 16384 + wv * 1024);
            gll16(gv + 262144, nbuf + 24576 + wv * 1024);
        }

        // K fragments (shared across both q-tiles)
        const char* kr = buf + krowOff;
        bf16x8 kf00 = *(const bf16x8*)(kr + kA);
        bf16x8 kf01 = *(const bf16x8*)(kr + kB);
        bf16x8 kf10 = *(const bf16x8*)(kr + 2048 + kA);
        bf16x8 kf11 = *(const bf16x8*)(kr + 2048 + kB);

        // S^T = mfma(K, Q): lane -> S[key=kg*32+16*kt+4*quad+r][q=qg*32+16*qt+l16]
        f32x4 s[2][2];
        __builtin_amdgcn_s_setprio(1);
        #pragma unroll
        for (int qt = 0; qt < 2; qt++) {
            f32x4 a0 = (f32x4)0.f, a1 = (f32x4)0.f;
            a0 = mfma16(kf00, qm[qt][0], a0);
            a0 = mfma16(kf01, qm[qt][1], a0);
            a1 = mfma16(kf10, qm[qt][0], a1);
            a1 = mfma16(kf11, qm[qt][1], a1);
            s[qt][0] = a0; s[qt][1] = a1;
        }
        __builtin_amdgcn_s_setprio(0);

        const int hp = 2 * j + (kg >> 1);
        bf16x8 pa[2];
        #pragma unroll
        for (int qt = 0; qt < 2; qt++) {
            float rhb = LOG2E * __bfloat162float((qt ? rh1 : rh0)[hp]);
            float pv[8];
            #pragma unroll
            for (int r = 0; r < 4; r++)
                pv[r] = __builtin_amdgcn_exp2f(fmaf(s[qt][0][r], SC, rwf[qt][0][r] + rhb));
            #pragma unroll
            for (int r = 0; r < 4; r++)
                pv[4 + r] = __builtin_amdgcn_exp2f(fmaf(s[qt][1][r], SC, rwf[qt][1][r] + rhb));
            union { bf16x8 v; __hip_bfloat162 b2[4]; } pu;
            #pragma unroll
            for (int pi = 0; pi < 4; pi++)
                pu.b2[pi] = __float22bfloat162_rn(float2{pv[2 * pi], pv[2 * pi + 1]});
            pa[qt] = pu.v;   // slot e=4*kt+r matches vt slot layout
        }

        // O += P V ; l += P . ones  (contracts the wave's full 32 keys)
        __builtin_amdgcn_s_setprio(1);
        #pragma unroll
        for (int dt = 0; dt < 4; dt++) {
            bf16x8 vf = *(const bf16x8*)(buf + vOff + dt * 4096);
            oacc[0][dt] = mfma16(pa[0], vf, oacc[0][dt]);
            oacc[1][dt] = mfma16(pa[1], vf, oacc[1][dt]);
        }
        lacc[0] = mfma16(pa[0], vones, lacc[0]);
        lacc[1] = mfma16(pa[1], vones, lacc[1]);
        __builtin_amdgcn_s_setprio(0);
        __syncthreads();   // drains this wave's DMA (next tile) + releases buffers
    }

    // ---- epilogue: single-round combine of the 4 key-slices ----
    // regions (kg-1) in smem: 4608 floats oacc + 64 floats lacc = 4672 each (3x = 56 KB)
    float* obuf = (float*)smem;
    if (kg != 0) {
        float* rb = obuf + (kg - 1) * 4672;
        #pragma unroll
        for (int qt = 0; qt < 2; qt++)
            #pragma unroll
            for (int dt = 0; dt < 4; dt++)
                *(f32x4*)&rb[qg * 2304 + (16 * dt + l16) * 36 + 16 * qt + 4 * quad]
                    = oacc[qt][dt];
        if (l16 == 0)
            #pragma unroll
            for (int qt = 0; qt < 2; qt++)
                #pragma unroll
                for (int r = 0; r < 4; r++)
                    rb[4608 + qg * 32 + 16 * qt + 4 * quad + r] = lacc[qt][r];
    }
    __syncthreads();
    if (kg == 0) {
        #pragma unroll
        for (int rg = 0; rg < 3; rg++) {
            const float* rb = obuf + rg * 4672;
            #pragma unroll
            for (int qt = 0; qt < 2; qt++) {
                #pragma unroll
                for (int dt = 0; dt < 4; dt++)
                    oacc[qt][dt] += *(const f32x4*)&rb[qg * 2304 + (16 * dt + l16) * 36
                                                       + 16 * qt + 4 * quad];
                #pragma unroll
                for (int r = 0; r < 4; r++)
                    lacc[qt][r] += rb[4608 + qg * 32 + 16 * qt + 4 * quad + r];
            }
        }
        const int b = bh >> 2, head = bh & 3;
        #pragma unroll
        for (int qt = 0; qt < 2; qt++) {
            f32x4 lv;
            #pragma unroll
            for (int r = 0; r < 4; r++) lv[r] = 1.f / lacc[qt][r];
            #pragma unroll
            for (int dt = 0; dt < 4; dt++) {
                f32x4 o = oacc[qt][dt] * lv;
                int dv = 16 * dt + l16;
                int q0 = qg * 32 + 16 * qt + 4 * quad;
                *(f32x4*)&out[((size_t)(b * 256 + head * 64 + dv)) * 4096 + h * 64 + q0] = o;
            }
        }
    }
}

extern "C" void kernel_launch(void* const* d_in, const int* in_sizes, int n_in,
                              void* d_out, int out_size, void* d_ws, size_t ws_size,
                              hipStream_t stream) {
    const float* x     = (const float*)d_in[0];
    const float* qkv_w = (const float*)d_in[1];
    const float* hrel  = (const float*)d_in[2];
    const float* wrel  = (const float*)d_in[3];
    float* out = (float*)d_out;

    __hip_bfloat16* qb = (__hip_bfloat16*)d_ws;
    __hip_bfloat16* kb = qb + (size_t)8 * 4096 * 64;
    __hip_bfloat16* vt = kb + (size_t)8 * 4096 * 64;

    qkv_kernel<<<dim3(64, 6, 2), 256, 0, stream>>>(x, qkv_w, qb, kb, vt);
    attn_kernel<<<dim3(64, 8), 512, 65536, stream>>>(qb, kb, vt, hrel, wrel, out);
}